// Round 1
// baseline (1119.802 us; speedup 1.0000x reference)
//
#include <hip/hip_runtime.h>

#define TT 512
#define HH 64

typedef __attribute__((ext_vector_type(8))) short bf16x8;
typedef __attribute__((ext_vector_type(4))) float f32x4;

__device__ inline short f2bf(float f) {
    // round-to-nearest-even fp32 -> bf16 (values are bounded/sane here; no NaN path needed)
    unsigned u = __float_as_uint(f);
    u += 0x7FFFu + ((u >> 16) & 1u);
    return (short)(u >> 16);
}

// NaN-safe saturating fast activations (div-by-inf -> 0):
__device__ inline float sigm(float x)  { return __fdividef(1.0f, 1.0f + __expf(-x)); }
__device__ inline float tanh_(float x) { return 1.0f - __fdividef(2.0f, 1.0f + __expf(2.0f * x)); }

// WG layout: 384 threads = 6 waves. wave = (layer L in 0..2) x (unit-half hf in 0..1).
// Each WG owns 4 batch rows for the entire T loop (grid = 256 WGs = 1/CU).
// Per wave, per step: pre-act[4rows x 96cols-of-its-half] via MFMA 16x16x32 bf16,
// weights resident in B-frag registers, h carried fp32 in C-layout registers,
// layer handoff via double-buffered LDS (bf16, A-frag-readable row-major stride 72).
__global__ __launch_bounds__(384, 2)
void gru_fused(const float* __restrict__ x,
               const float* __restrict__ Wih0, const float* __restrict__ Whh0,
               const float* __restrict__ bih0, const float* __restrict__ bhh0,
               const float* __restrict__ Wih1, const float* __restrict__ Whh1,
               const float* __restrict__ bih1, const float* __restrict__ bhh1,
               const float* __restrict__ Wih2, const float* __restrict__ Whh2,
               const float* __restrict__ bih2, const float* __restrict__ bhh2,
               const float* __restrict__ fc1w, const float* __restrict__ fc1b,
               const float* __restrict__ fc2w, const float* __restrict__ fc2b,
               float* __restrict__ out)
{
    // 16 rows x 72 bf16 (64 cols + 8 pad -> 144B row stride: 16B-aligned frags, even bank spread)
    __shared__ __align__(16) short hbuf[3][2][16 * 72];
    __shared__ __align__(16) short xbuf[2][16 * 72];
    __shared__ float h2out[4][64];
    __shared__ float fcz[4][32];

    const int tid = threadIdx.x;
    const int l   = tid & 63;
    const int wid = tid >> 6;   // 0..5
    const int L   = wid >> 1;   // layer 0..2
    const int hf  = wid & 1;    // unit half: units hf*32 .. hf*32+31
    const int n_  = l & 15;     // A-frag row (m) / B-frag col / C col
    const int q   = l >> 4;     // quad
    const int rbase = blockIdx.x * 4;

    // ---- zero LDS h/x buffers (h(-1)=0; x pad cols stay 0) ----
    for (int i = tid; i < 3 * 2 * 16 * 72; i += 384) (&hbuf[0][0][0])[i] = 0;
    for (int i = tid; i < 2 * 16 * 72; i += 384) (&xbuf[0][0])[i] = 0;
    __syncthreads();
    // preload x(t=0) into xbuf[0]: lane -> (row=l>>4, k=l&15)
    if (wid == 0) {
        float v = x[((rbase + (l >> 4)) * TT + 0) * 16 + (l & 15)];
        xbuf[0][(l >> 4) * 72 + (l & 15)] = f2bf(v);
    }

    // ---- per-wave weight selection ----
    const float* Wih = (L == 0) ? Wih0 : (L == 1) ? Wih1 : Wih2;
    const float* Whh = (L == 0) ? Whh0 : (L == 1) ? Whh1 : Whh2;
    const float* bih = (L == 0) ? bih0 : (L == 1) ? bih1 : bih2;
    const float* bhh = (L == 0) ? bhh0 : (L == 1) ? bhh1 : bhh2;
    const int ldih = (L == 0) ? 16 : 64;   // W_ih0 is [192,16]; K zero-padded to 64

    // ---- resident B-frags: nt 0,1 = r-cols, 2,3 = z-cols, 4,5 = n-cols (this half) ----
    // B-frag lane layout: B[k][n] with n = l&15 (col), k = kt*32 + q*8 + j
    bf16x8 wihf[6][2], whhf[6][2];
#pragma unroll
    for (int nt = 0; nt < 6; ++nt) {
        const int gcol = (nt >> 1) * 64 + hf * 32 + (nt & 1) * 16;
#pragma unroll
        for (int kt = 0; kt < 2; ++kt) {
            const int kb = kt * 32 + q * 8;
            bf16x8 fi, fh;
#pragma unroll
            for (int j = 0; j < 8; ++j) {
                const int k = kb + j;
                float vi = (k < ldih) ? Wih[(gcol + n_) * ldih + k] : 0.0f;
                float vh = Whh[(gcol + n_) * 64 + k];
                fi[j] = f2bf(vi);
                fh[j] = f2bf(vh);
            }
            wihf[nt][kt] = fi;
            whhf[nt][kt] = fh;
        }
    }

    // ---- resident per-lane biases (col = gcol + n_) ----
    float brz[4], bxn[2], bhn[2];
#pragma unroll
    for (int nt = 0; nt < 4; ++nt) {
        const int c = (nt >> 1) * 64 + hf * 32 + (nt & 1) * 16 + n_;
        brz[nt] = bih[c] + bhh[c];
    }
#pragma unroll
    for (int i2 = 0; i2 < 2; ++i2) {
        const int c = 128 + hf * 32 + i2 * 16 + n_;
        bxn[i2] = bih[c];
        bhn[i2] = bhh[c];
    }

    // fp32 h state, C layout: hprev[i2][r] = h[row=q*4+r][unit hf*32+i2*16+n_]
    f32x4 hprev[2];
    hprev[0] = (f32x4){0.f, 0.f, 0.f, 0.f};
    hprev[1] = (f32x4){0.f, 0.f, 0.f, 0.f};

    __syncthreads();

    // ---- pipelined time loop: wave L processes t = s - L ----
    for (int s = 0; s < TT + 2; ++s) {
        // prefetch x(s+1) (wave 0 only), consumed at end of step
        float xr = 0.0f;
        const bool xload = (wid == 0) && (s + 1 < TT);
        if (xload) xr = x[((rbase + (l >> 4)) * TT + (s + 1)) * 16 + (l & 15)];

        const int tw = s - L;
        if (tw >= 0 && tw < TT) {
            const int bi = tw & 1;       // input h_{L-1}(tw) buffer, and our write buffer
            const int bo = bi ^ 1;       // own h_L(tw-1) buffer
            const short* inp = (L == 0) ? &xbuf[bi][0] : &hbuf[L - 1][bi][0];
            const short* own = &hbuf[L][bo][0];

            // A-frags (A[m=n_][k=kt*32+q*8+j]): 16B-aligned ds_read_b128
            bf16x8 iA0 = *(const bf16x8*)(inp + n_ * 72 + q * 8);
            bf16x8 iA1 = *(const bf16x8*)(inp + n_ * 72 + 32 + q * 8);
            bf16x8 hA0 = *(const bf16x8*)(own + n_ * 72 + q * 8);
            bf16x8 hA1 = *(const bf16x8*)(own + n_ * 72 + 32 + q * 8);

            f32x4 crz[4], cxn[2], chn[2];
#pragma unroll
            for (int i = 0; i < 4; ++i) crz[i] = (f32x4){0.f, 0.f, 0.f, 0.f};
#pragma unroll
            for (int i = 0; i < 2; ++i) { cxn[i] = (f32x4){0.f, 0.f, 0.f, 0.f}; chn[i] = (f32x4){0.f, 0.f, 0.f, 0.f}; }

            // r,z pre-acts: x@Wih^T + h@Whh^T accumulated into one C
#pragma unroll
            for (int nt = 0; nt < 4; ++nt) {
                crz[nt] = __builtin_amdgcn_mfma_f32_16x16x32_bf16(iA0, wihf[nt][0], crz[nt], 0, 0, 0);
                crz[nt] = __builtin_amdgcn_mfma_f32_16x16x32_bf16(iA1, wihf[nt][1], crz[nt], 0, 0, 0);
                crz[nt] = __builtin_amdgcn_mfma_f32_16x16x32_bf16(hA0, whhf[nt][0], crz[nt], 0, 0, 0);
                crz[nt] = __builtin_amdgcn_mfma_f32_16x16x32_bf16(hA1, whhf[nt][1], crz[nt], 0, 0, 0);
            }
            // n pre-acts kept separate (bias b_hh_n sits inside r*hn)
#pragma unroll
            for (int i2 = 0; i2 < 2; ++i2) {
                cxn[i2] = __builtin_amdgcn_mfma_f32_16x16x32_bf16(iA0, wihf[4 + i2][0], cxn[i2], 0, 0, 0);
                cxn[i2] = __builtin_amdgcn_mfma_f32_16x16x32_bf16(iA1, wihf[4 + i2][1], cxn[i2], 0, 0, 0);
                chn[i2] = __builtin_amdgcn_mfma_f32_16x16x32_bf16(hA0, whhf[4 + i2][0], chn[i2], 0, 0, 0);
                chn[i2] = __builtin_amdgcn_mfma_f32_16x16x32_bf16(hA1, whhf[4 + i2][1], chn[i2], 0, 0, 0);
            }

            // gate math in C layout (r/z/n tiles share lane+reg mapping per unit)
            short* op = &hbuf[L][bi][0];
#pragma unroll
            for (int i2 = 0; i2 < 2; ++i2) {
#pragma unroll
                for (int r = 0; r < 4; ++r) {
                    float rr = sigm(crz[i2][r] + brz[i2]);
                    float zz = sigm(crz[2 + i2][r] + brz[2 + i2]);
                    float nn = tanh_(cxn[i2][r] + bxn[i2] + rr * (chn[i2][r] + bhn[i2]));
                    float hp = hprev[i2][r];
                    float hv = nn + zz * (hp - nn);
                    hprev[i2][r] = hv;
                    op[(q * 4 + r) * 72 + hf * 32 + i2 * 16 + n_] = f2bf(hv);
                }
            }
        }
        if (xload) xbuf[(s + 1) & 1][(l >> 4) * 72 + (l & 15)] = f2bf(xr);
        __syncthreads();
    }

    // ---- FC head: h2(T-1) lives in L2 waves' hprev (valid rows = q==0, m=r) ----
    if (wid >= 4 && q == 0) {
#pragma unroll
        for (int i2 = 0; i2 < 2; ++i2)
#pragma unroll
            for (int r = 0; r < 4; ++r)
                h2out[r][hf * 32 + i2 * 16 + n_] = hprev[i2][r];
    }
    __syncthreads();
    if (tid < 128) {
        const int row = tid >> 5, u = tid & 31;
        float acc = fc1b[u];
#pragma unroll
        for (int k = 0; k < 64; ++k) acc += h2out[row][k] * fc1w[u * 64 + k];
        fcz[row][u] = fmaxf(acc, 0.0f);
    }
    __syncthreads();
    if (tid < 4) {
        float y = fc2b[0];
#pragma unroll
        for (int u = 0; u < 32; ++u) y += fcz[tid][u] * fc2w[u];
        out[rbase + tid] = y;
    }
}

extern "C" void kernel_launch(void* const* d_in, const int* in_sizes, int n_in,
                              void* d_out, int out_size, void* d_ws, size_t ws_size,
                              hipStream_t stream) {
    (void)in_sizes; (void)n_in; (void)d_ws; (void)ws_size; (void)out_size;
    gru_fused<<<dim3(256), dim3(384), 0, stream>>>(
        (const float*)d_in[0],
        (const float*)d_in[1],  (const float*)d_in[2],  (const float*)d_in[3],  (const float*)d_in[4],
        (const float*)d_in[5],  (const float*)d_in[6],  (const float*)d_in[7],  (const float*)d_in[8],
        (const float*)d_in[9],  (const float*)d_in[10], (const float*)d_in[11], (const float*)d_in[12],
        (const float*)d_in[13], (const float*)d_in[14], (const float*)d_in[15], (const float*)d_in[16],
        (float*)d_out);
}

// Round 2
// 522.209 us; speedup vs baseline: 2.1444x; 2.1444x over previous
//
#include <hip/hip_runtime.h>

#define TT 512

typedef __attribute__((ext_vector_type(8))) short bf16x8;
typedef __attribute__((ext_vector_type(4))) float f32x4;

__device__ inline short f2bf(float f) {
    // round-to-nearest-even fp32 -> bf16 (values bounded; no NaN path needed)
    unsigned u = __float_as_uint(f);
    u += 0x7FFFu + ((u >> 16) & 1u);
    return (short)(u >> 16);
}

__device__ inline float sigm(float x)  { return __fdividef(1.0f, 1.0f + __expf(-x)); }
__device__ inline float tanh_(float x) { return 1.0f - __fdividef(2.0f, 1.0f + __expf(2.0f * x)); }

// 768 threads = 12 waves = 3 layers x 4 unit-quarters (16 units each).
// WG owns 4 batch rows for all T; grid = 256 = 1 WG/CU; 3 waves/SIMD balanced.
// Per wave/step: 12 MFMA (weights resident in B-frags), valid C rows (q==0 lanes)
// scattered to per-wave LDS scratch, re-read so each lane does gate math for
// exactly ONE h-unit (no garbage-row transcendentals). One barrier per step.
__global__ __launch_bounds__(768, 1)
void gru_fused(const float* __restrict__ x,
               const float* __restrict__ Wih0, const float* __restrict__ Whh0,
               const float* __restrict__ bih0, const float* __restrict__ bhh0,
               const float* __restrict__ Wih1, const float* __restrict__ Whh1,
               const float* __restrict__ bih1, const float* __restrict__ bhh1,
               const float* __restrict__ Wih2, const float* __restrict__ Whh2,
               const float* __restrict__ bih2, const float* __restrict__ bhh2,
               const float* __restrict__ fc1w, const float* __restrict__ fc1b,
               const float* __restrict__ fc2w, const float* __restrict__ fc2b,
               float* __restrict__ out)
{
    // h/x buffers: 4 valid rows only (A-frag reads are exec-masked to n_<4);
    // row stride 72 shorts = 144B (16B-aligned frags). Pad cols stay zero.
    __shared__ __align__(16) short hbuf[3][2][4 * 72];
    __shared__ __align__(16) short xbuf[2][4 * 72];
    // per-wave preact scratch: [tile r/z/xn/hn][col 16][row 4] -> exact 2-way banks
    __shared__ __align__(16) float pre[12][4][16][4];
    __shared__ float h2out[4][64];
    __shared__ float fcz[4][32];

    const int tid = threadIdx.x;
    const int l   = tid & 63;
    const int wid = tid >> 6;   // 0..11
    const int L   = wid >> 2;   // layer 0..2
    const int qt  = wid & 3;    // unit quarter: units qt*16 .. qt*16+15
    const int n_  = l & 15;     // A-frag row / B-frag col / C col
    const int q   = l >> 4;     // quad
    const int rbase = blockIdx.x * 4;

    // distributed gate-lane assignment: one h-unit per lane
    const int grow = l >> 4;          // batch row 0..3
    const int gcol = l & 15;          // col within quarter
    const int u    = qt * 16 + gcol;  // unit 0..63

    // ---- zero LDS h/x buffers (h(-1)=0; pads stay 0) ----
    for (int i = tid; i < 3 * 2 * 4 * 72; i += 768) (&hbuf[0][0][0])[i] = 0;
    for (int i = tid; i < 2 * 4 * 72; i += 768) (&xbuf[0][0])[i] = 0;
    __syncthreads();
    if (wid == 0) {
        float v = x[((rbase + (l >> 4)) * TT + 0) * 16 + (l & 15)];
        xbuf[0][(l >> 4) * 72 + (l & 15)] = f2bf(v);
    }

    // ---- per-wave weight selection ----
    const float* Wih = (L == 0) ? Wih0 : (L == 1) ? Wih1 : Wih2;
    const float* Whh = (L == 0) ? Whh0 : (L == 1) ? Whh1 : Whh2;
    const float* bih = (L == 0) ? bih0 : (L == 1) ? bih1 : bih2;
    const float* bhh = (L == 0) ? bhh0 : (L == 1) ? bhh1 : bhh2;
    const int ldih = (L == 0) ? 16 : 64;   // W_ih0 is [192,16]; K zero-padded

    // ---- resident B-frags: gate g in {0=r,1=z,2=n}, cols g*64+qt*16.. ----
    // B-frag lane layout: col = n_, k = kt*32 + q*8 + j
    bf16x8 wihf[3][2], whhf[3][2];
#pragma unroll
    for (int g = 0; g < 3; ++g) {
        const int gc = g * 64 + qt * 16;
#pragma unroll
        for (int kt = 0; kt < 2; ++kt) {
            const int kb = kt * 32 + q * 8;
            bf16x8 fi, fh;
#pragma unroll
            for (int j = 0; j < 8; ++j) {
                const int k = kb + j;
                float vi = (k < ldih) ? Wih[(gc + n_) * ldih + k] : 0.0f;
                float vh = Whh[(gc + n_) * 64 + k];
                fi[j] = f2bf(vi);
                fh[j] = f2bf(vh);
            }
            wihf[g][kt] = fi;
            whhf[g][kt] = fh;
        }
    }

    // ---- per-lane gate biases (for this lane's single unit) ----
    const float br  = bih[u] + bhh[u];
    const float bz  = bih[64 + u] + bhh[64 + u];
    const float bxn = bih[128 + u];
    const float bhn = bhh[128 + u];
    float hp = 0.0f;   // this lane's h(row=grow, unit=u), carried fp32

    __syncthreads();

    // ---- pipelined time loop: wave of layer L processes t = s - L ----
    for (int s = 0; s < TT + 2; ++s) {
        float xr = 0.0f;
        const bool xload = (wid == 0) && (s + 1 < TT);
        if (xload) xr = x[((rbase + (l >> 4)) * TT + (s + 1)) * 16 + (l & 15)];

        const int tw = s - L;
        if (tw >= 0 && tw < TT) {
            const int bi = tw & 1;
            const int bo = bi ^ 1;
            const short* inp = (L == 0) ? &xbuf[bi][0] : &hbuf[L - 1][bi][0];
            const short* own = &hbuf[L][bo][0];

            // A-frags: only rows 0..3 are real; lanes n_>=4 contribute zeros
            bf16x8 iA0 = {0,0,0,0,0,0,0,0}, iA1 = {0,0,0,0,0,0,0,0};
            bf16x8 hA0 = {0,0,0,0,0,0,0,0}, hA1 = {0,0,0,0,0,0,0,0};
            if (n_ < 4) {
                iA0 = *(const bf16x8*)(inp + n_ * 72 + q * 8);
                iA1 = *(const bf16x8*)(inp + n_ * 72 + 32 + q * 8);
                hA0 = *(const bf16x8*)(own + n_ * 72 + q * 8);
                hA1 = *(const bf16x8*)(own + n_ * 72 + 32 + q * 8);
            }

            f32x4 cr  = {0.f, 0.f, 0.f, 0.f};
            f32x4 cz  = {0.f, 0.f, 0.f, 0.f};
            f32x4 cxn = {0.f, 0.f, 0.f, 0.f};
            f32x4 chn = {0.f, 0.f, 0.f, 0.f};
            cr  = __builtin_amdgcn_mfma_f32_16x16x32_bf16(iA0, wihf[0][0], cr, 0, 0, 0);
            cr  = __builtin_amdgcn_mfma_f32_16x16x32_bf16(iA1, wihf[0][1], cr, 0, 0, 0);
            cr  = __builtin_amdgcn_mfma_f32_16x16x32_bf16(hA0, whhf[0][0], cr, 0, 0, 0);
            cr  = __builtin_amdgcn_mfma_f32_16x16x32_bf16(hA1, whhf[0][1], cr, 0, 0, 0);
            cz  = __builtin_amdgcn_mfma_f32_16x16x32_bf16(iA0, wihf[1][0], cz, 0, 0, 0);
            cz  = __builtin_amdgcn_mfma_f32_16x16x32_bf16(iA1, wihf[1][1], cz, 0, 0, 0);
            cz  = __builtin_amdgcn_mfma_f32_16x16x32_bf16(hA0, whhf[1][0], cz, 0, 0, 0);
            cz  = __builtin_amdgcn_mfma_f32_16x16x32_bf16(hA1, whhf[1][1], cz, 0, 0, 0);
            cxn = __builtin_amdgcn_mfma_f32_16x16x32_bf16(iA0, wihf[2][0], cxn, 0, 0, 0);
            cxn = __builtin_amdgcn_mfma_f32_16x16x32_bf16(iA1, wihf[2][1], cxn, 0, 0, 0);
            chn = __builtin_amdgcn_mfma_f32_16x16x32_bf16(hA0, whhf[2][0], chn, 0, 0, 0);
            chn = __builtin_amdgcn_mfma_f32_16x16x32_bf16(hA1, whhf[2][1], chn, 0, 0, 0);

            // scatter valid C rows (q==0 lanes hold rows 0..3 in regs) to LDS;
            // intra-wave handoff -> ordered by lgkmcnt, no barrier needed
            if (q == 0) {
                *(f32x4*)&pre[wid][0][n_][0] = cr;
                *(f32x4*)&pre[wid][1][n_][0] = cz;
                *(f32x4*)&pre[wid][2][n_][0] = cxn;
                *(f32x4*)&pre[wid][3][n_][0] = chn;
            }
            const float pr  = pre[wid][0][gcol][grow];
            const float pz  = pre[wid][1][gcol][grow];
            const float pxn = pre[wid][2][gcol][grow];
            const float phn = pre[wid][3][gcol][grow];

            // one h-unit per lane
            const float rr = sigm(pr + br);
            const float zz = sigm(pz + bz);
            const float nn = tanh_(pxn + bxn + rr * (phn + bhn));
            const float hv = nn + zz * (hp - nn);
            hp = hv;
            hbuf[L][bi][grow * 72 + u] = f2bf(hv);
        }
        if (xload) xbuf[(s + 1) & 1][(l >> 4) * 72 + (l & 15)] = f2bf(xr);
        __syncthreads();
    }

    // ---- FC head: L2 waves hold h2(T-1), one value per lane ----
    if (wid >= 8) h2out[grow][u] = hp;
    __syncthreads();
    if (tid < 128) {
        const int row = tid >> 5, uu = tid & 31;
        float acc = fc1b[uu];
#pragma unroll
        for (int k = 0; k < 64; ++k) acc += h2out[row][k] * fc1w[uu * 64 + k];
        fcz[row][uu] = fmaxf(acc, 0.0f);
    }
    __syncthreads();
    if (tid < 4) {
        float y = fc2b[0];
#pragma unroll
        for (int uu = 0; uu < 32; ++uu) y += fcz[tid][uu] * fc2w[uu];
        out[rbase + tid] = y;
    }
}

extern "C" void kernel_launch(void* const* d_in, const int* in_sizes, int n_in,
                              void* d_out, int out_size, void* d_ws, size_t ws_size,
                              hipStream_t stream) {
    (void)in_sizes; (void)n_in; (void)d_ws; (void)ws_size; (void)out_size;
    gru_fused<<<dim3(256), dim3(768), 0, stream>>>(
        (const float*)d_in[0],
        (const float*)d_in[1],  (const float*)d_in[2],  (const float*)d_in[3],  (const float*)d_in[4],
        (const float*)d_in[5],  (const float*)d_in[6],  (const float*)d_in[7],  (const float*)d_in[8],
        (const float*)d_in[9],  (const float*)d_in[10], (const float*)d_in[11], (const float*)d_in[12],
        (const float*)d_in[13], (const float*)d_in[14], (const float*)d_in[15], (const float*)d_in[16],
        (float*)d_out);
}